// Round 4
// baseline (126.321 us; speedup 1.0000x reference)
//
#include <hip/hip_runtime.h>

#define B_ 4
#define H_ 8
#define LQ_ 256
#define LK_ 256
#define DK_ 64
#define BH_ (B_*H_)           // 32
#define NROWS (BH_*LQ_)       // 8192 rows per projection
#define QT 4                  // q rows per block in fused score kernel

// ---------------- K1: projections qp = q*Wq^T + bq, kp = k*Wk^T + bk ----
// grid 512: blocks [0,256) -> q-proj, [256,512) -> k-proj; 32 rows/block.
// W staged in LDS at stride 68; e = gg + i*8 so the 8 lane-groups read
// banks {4g..4g+3} -> conflict-free (68%32=4; e=gg*8+i would be 8-way).
__global__ __launch_bounds__(256) void proj_kernel(
    const float* __restrict__ qin, const float* __restrict__ kin,
    const float* __restrict__ Wq, const float* __restrict__ bq,
    const float* __restrict__ Wk, const float* __restrict__ bk,
    float* __restrict__ qp, float* __restrict__ kp)
{
    const int which = blockIdx.x >> 8;           // 0 = q, 1 = k
    const int rb    = (blockIdx.x & 255) * 32;   // first row of this block
    const float* in   = which ? kin : qin;
    const float* W    = which ? Wk  : Wq;
    const float* bias = which ? bk  : bq;
    float* out        = which ? kp  : qp;

    __shared__ float in_s[32*68];
    __shared__ float w_s[64*68];
    const int tid = threadIdx.x;

    {
        const float4* g = (const float4*)(in + rb*64);
        #pragma unroll
        for (int p = 0; p < 2; ++p) {
            int f = tid + p*256;
            float4 x = g[f];
            *(float4*)&in_s[(f>>4)*68 + (f&15)*4] = x;
        }
    }
    {
        const float4* g = (const float4*)W;
        #pragma unroll
        for (int p = 0; p < 4; ++p) {
            int f = tid + p*256;
            float4 x = g[f];
            *(float4*)&w_s[(f>>4)*68 + (f&15)*4] = x;
        }
    }
    __syncthreads();

    const int r  = tid >> 3;                     // 0..31 row
    const int gg = tid & 7;                      // e = gg + i*8
    float acc[8];
    #pragma unroll
    for (int i = 0; i < 8; ++i) acc[i] = 0.f;

    #pragma unroll
    for (int j = 0; j < 16; ++j) {
        float4 x = *(const float4*)&in_s[r*68 + j*4];   // 8-lane broadcast
        #pragma unroll
        for (int i = 0; i < 8; ++i) {
            float4 w = *(const float4*)&w_s[(gg + i*8)*68 + j*4]; // cf-free
            acc[i] = fmaf(w.x, x.x, acc[i]);
            acc[i] = fmaf(w.y, x.y, acc[i]);
            acc[i] = fmaf(w.z, x.z, acc[i]);
            acc[i] = fmaf(w.w, x.w, acc[i]);
        }
    }
    float* orow = out + (rb + r)*64;
    #pragma unroll
    for (int i = 0; i < 8; ++i) {
        const int e = gg + i*8;
        orow[e] = acc[i] + bias[e];
    }
}

// ---------------- K2: scores + softmax + attn-write + PV (fused) --------
// grid = BH_ * (LQ_/QT) = 2048 blocks, 256 threads. Thread t owns k = t.
// score = vs_b + sum(vs) - 2 * sum_d vs[d] * rcp(exp2(C2*qp_d + C2*kp_d) + 1)
// qp (LDS) and kp (regs) pre-scaled by C2 = 2*log2(e).
// kp processed in QUARTERS (kr[4] = 16 VGPRs live), unroll 1 on the quarter
// loop so loads can't be hoisted (R1: 256 VGPR spill; R2: forced-64 spill ->
// 1.1 GB scratch. Keep the natural live set small; no min-waves forcing.)
// No max-subtraction: |score| <= |vs_b| + sum|vs| <= ~8.2 -> exp safe in fp32.
// PV fused (R4): attn tile -> LDS, one barrier, thread (q=t>>6, d=t&63) does
// a 256-MAC dot with coalesced global v reads (v[bh]=64 KB, L1/L2-resident).
// Kills the separate pv_kernel launch + 8.4 MB attn HBM re-read.
__global__ __launch_bounds__(256) void score_softmax_pv_kernel(
    const float* __restrict__ qp, const float* __restrict__ kp,
    const float* __restrict__ vs_w, const float* __restrict__ vs_b,
    const float* __restrict__ v,
    float* __restrict__ attn, float* __restrict__ out)
{
    const int bh = blockIdx.x >> 6;          // LQ_/QT = 64 chunks per bh
    const int qt = blockIdx.x & 63;
    const int t  = threadIdx.x;
    const int lane = t & 63, wid = t >> 6;

    const float C2  = 2.8853900817779268f;   // 2*log2(e)
    const float L2E = 1.4426950408889634f;

    __shared__ float qp_s[QT*64];            // pre-scaled by C2
    __shared__ float vs_s[64];
    __shared__ float reds[QT][4];
    __shared__ float a_s[QT*256];            // normalized attn tile

    if (t < QT*16) {
        float4 x = ((const float4*)(qp + (bh*LQ_ + qt*QT)*64))[t];
        x.x *= C2; x.y *= C2; x.z *= C2; x.w *= C2;
        ((float4*)qp_s)[t] = x;
    } else if (t < QT*16 + 64) {
        vs_s[t - QT*16] = vs_w[t - QT*16];
    }
    __syncthreads();

    // base = vs_b + sum(vs)   (LDS broadcast reads)
    float S = vs_b[0];
    #pragma unroll
    for (int j = 0; j < 16; ++j) {
        float4 w = *(const float4*)&vs_s[j*4];
        S += (w.x + w.y) + (w.z + w.w);
    }

    const float4* kg = (const float4*)(kp + (bh*LK_ + t)*64);

    float sc[QT] = {0.f, 0.f, 0.f, 0.f};
    #pragma unroll 1
    for (int quar = 0; quar < 4; ++quar) {
        float4 kr[4];                        // 16 VGPRs live
        #pragma unroll
        for (int j = 0; j < 4; ++j) {
            float4 kv = kg[quar*4 + j];
            kr[j].x = kv.x*C2; kr[j].y = kv.y*C2;
            kr[j].z = kv.z*C2; kr[j].w = kv.w*C2;
        }
        #pragma unroll
        for (int q = 0; q < QT; ++q) {
            float a0 = 0.f, a1 = 0.f;
            #pragma unroll
            for (int j = 0; j < 4; ++j) {
                float4 qv = *(const float4*)&qp_s[q*64 + quar*16 + j*4]; // bcast
                float4 wv = *(const float4*)&vs_s[quar*16 + j*4];        // bcast
                float4 kv = kr[j];
                a0 = fmaf(wv.x, __builtin_amdgcn_rcpf(__builtin_amdgcn_exp2f(qv.x+kv.x)+1.f), a0);
                a1 = fmaf(wv.y, __builtin_amdgcn_rcpf(__builtin_amdgcn_exp2f(qv.y+kv.y)+1.f), a1);
                a0 = fmaf(wv.z, __builtin_amdgcn_rcpf(__builtin_amdgcn_exp2f(qv.z+kv.z)+1.f), a0);
                a1 = fmaf(wv.w, __builtin_amdgcn_rcpf(__builtin_amdgcn_exp2f(qv.w+kv.w)+1.f), a1);
            }
            sc[q] += a0 + a1;
        }
    }

    // p = exp(score); sum over k (no max subtraction; scores bounded)
    float p[QT];
    #pragma unroll
    for (int q = 0; q < QT; ++q) {
        p[q] = __builtin_amdgcn_exp2f((S - 2.f*sc[q]) * L2E);
        float s = p[q];
        #pragma unroll
        for (int off = 32; off; off >>= 1) s += __shfl_xor(s, off, 64);
        if (lane == 0) reds[q][wid] = s;
    }
    __syncthreads();
    #pragma unroll
    for (int q = 0; q < QT; ++q) {
        float s = (reds[q][0] + reds[q][1]) + (reds[q][2] + reds[q][3]);
        float a = p[q] * __builtin_amdgcn_rcpf(s);
        attn[(bh*LQ_ + qt*QT + q)*LK_ + t] = a;   // coalesced global
        a_s[q*256 + t] = a;                       // stride-1: conflict-free
    }
    __syncthreads();

    // PV: thread (q = t>>6, d = t&63); wave q is uniform -> a_s reads are
    // b128 broadcasts; v reads are 256 B contiguous per wave instr.
    {
        const int q = t >> 6, d = t & 63;
        const float* vb = v + bh*LK_*DK_ + d;
        float acc = 0.f;
        #pragma unroll 4
        for (int k4 = 0; k4 < 64; ++k4) {
            float4 a4 = *(const float4*)&a_s[q*256 + k4*4];
            acc = fmaf(a4.x, vb[(k4*4+0)*64], acc);
            acc = fmaf(a4.y, vb[(k4*4+1)*64], acc);
            acc = fmaf(a4.z, vb[(k4*4+2)*64], acc);
            acc = fmaf(a4.w, vb[(k4*4+3)*64], acc);
        }
        out[(bh*LQ_ + qt*QT + q)*DK_ + d] = acc;  // 256 B/wave, coalesced
    }
}

extern "C" void kernel_launch(void* const* d_in, const int* in_sizes, int n_in,
                              void* d_out, int out_size, void* d_ws, size_t ws_size,
                              hipStream_t stream) {
    const float* q    = (const float*)d_in[0];
    const float* k    = (const float*)d_in[1];
    const float* v    = (const float*)d_in[2];
    const float* Wq_w = (const float*)d_in[3];
    const float* Wq_b = (const float*)d_in[4];
    const float* Wk_w = (const float*)d_in[5];
    const float* Wk_b = (const float*)d_in[6];
    const float* vs_w = (const float*)d_in[7];
    const float* vs_b = (const float*)d_in[8];

    float* out  = (float*)d_out;                      // [B,H,LQ,DK]
    float* attn = out + B_*H_*LQ_*DK_;                // [B,H,LQ,LK]
    float* qp   = (float*)d_ws;                       // 2 MB
    float* kp   = qp + NROWS*64;                      // 2 MB

    proj_kernel<<<512, 256, 0, stream>>>(q, k, Wq_w, Wq_b, Wk_w, Wk_b, qp, kp);
    score_softmax_pv_kernel<<<BH_*(LQ_/QT), 256, 0, stream>>>(
        qp, kp, vs_w, vs_b, v, attn, out);
}